// Round 3
// baseline (4761.509 us; speedup 1.0000x reference)
//
#include <hip/hip_runtime.h>
#include <hip/hip_bf16.h>

#define NL  3
#define NB  128
#define NT  256
#define NH  512
#define NH3 1536
#define NBH (NB*NH)      // 65536
#define NM  (NB*NT)      // 32768

typedef __bf16 bf16x8 __attribute__((ext_vector_type(8)));
typedef float  floatx4 __attribute__((ext_vector_type(4)));
typedef __hip_bfloat16 bf16;
typedef unsigned long long u64;

__device__ __forceinline__ floatx4 mfma16(bf16x8 a, bf16x8 b, floatx4 c) {
  return __builtin_amdgcn_mfma_f32_16x16x32_bf16(a, b, c, 0, 0, 0);
}
__device__ __forceinline__ void gload16(const void* g, void* l) {
  __builtin_amdgcn_global_load_lds(
      (const __attribute__((address_space(1))) unsigned int*)g,
      (__attribute__((address_space(3))) unsigned int*)l, 16, 0, 0);
}
__device__ __forceinline__ float fsig(float x)  { return 1.0f / (1.0f + __expf(-x)); }
__device__ __forceinline__ float ftanh(float x) { return 2.0f / (1.0f + __expf(-2.0f*x)) - 1.0f; }
__device__ __forceinline__ float b2f(unsigned short u) {
  unsigned v = (unsigned)u << 16; float f; __builtin_memcpy(&f, &v, 4); return f;
}
__device__ __forceinline__ unsigned short f2b(float f) {
  bf16 h = __float2bfloat16(f); unsigned short u; __builtin_memcpy(&u, &h, 2); return u;
}
__device__ __forceinline__ u64 ald(const u64* p) {
  return __hip_atomic_load(p, __ATOMIC_RELAXED, __HIP_MEMORY_SCOPE_AGENT);
}
__device__ __forceinline__ void ast(u64* p, u64 v) {
  __hip_atomic_store(p, v, __ATOMIC_RELAXED, __HIP_MEMORY_SCOPE_AGENT);
}

// ---------- transpose + cvt weights: fp32 [NL][NH][NH3] -> bf16 [NL][NH3][NH] ----------
__global__ void transpose_cvt_kernel(const float* __restrict__ in, bf16* __restrict__ out) {
  __shared__ float tile[32][33];
  int l = blockIdx.z;
  int n0 = blockIdx.x * 32, k0 = blockIdx.y * 32;
  const float* src = in + (size_t)l * NH * NH3;
  bf16* dst = out + (size_t)l * NH3 * NH;
  int tx = threadIdx.x, ty = threadIdx.y;    // 32 x 8
#pragma unroll
  for (int i = 0; i < 4; i++)
    tile[ty + 8*i][tx] = src[(size_t)(k0 + ty + 8*i) * NH3 + n0 + tx];
  __syncthreads();
#pragma unroll
  for (int i = 0; i < 4; i++)
    dst[(size_t)(n0 + ty + 8*i) * NH + k0 + tx] = __float2bfloat16(tile[tx][ty + 8*i]);
}

// ---------- elementwise fp32 -> bf16 (x input) ----------
__global__ void cvt_x_kernel(const float* __restrict__ in, bf16* __restrict__ out) {
  size_t i = (size_t)blockIdx.x * blockDim.x + threadIdx.x;
  float4 v = ((const float4*)in)[i];
  ushort4 pk;
  pk.x = f2b(v.x); pk.y = f2b(v.y); pk.z = f2b(v.z); pk.w = f2b(v.w);
  ((ushort4*)out)[i] = pk;
}

// ---------- xp GEMM (proven): C[m][n] = A[m]@Bt[n]^T + bias[n], bf16 out ----------
__global__ void __launch_bounds__(256, 2) gemm_xp_kernel(
    const bf16* __restrict__ A, const bf16* __restrict__ Bt,
    const float* __restrict__ bias, bf16* __restrict__ C, int a_mode)
{
  __shared__ char alds[16384];
  __shared__ char blds[16384];
  int tid = threadIdx.x;
  int lane = tid & 63, w = tid >> 6;
  int mblk = blockIdx.x, nblk = blockIdx.y;
  int wm = w >> 1, wn = w & 1;
  int klane = (lane >> 4) * 8;
  int r0 = 2*w*16 + (lane & 15);
  size_t arow0, arow1;
  if (a_mode == 0) {
    arow0 = ((size_t)r0 * NT + mblk) * NH;
    arow1 = ((size_t)(r0 + 16) * NT + mblk) * NH;
  } else {
    arow0 = (size_t)(mblk*128 + r0) * NH;
    arow1 = arow0 + (size_t)16 * NH;
  }
  size_t brow0 = (size_t)(nblk*128 + 2*w*16 + (lane & 15)) * NH;
  size_t brow1 = brow0 + (size_t)16 * NH;

  floatx4 acc[4][4];
#pragma unroll
  for (int i = 0; i < 4; i++)
#pragma unroll
    for (int j = 0; j < 4; j++) acc[i][j] = (floatx4){0.f, 0.f, 0.f, 0.f};

  for (int kk = 0; kk < 8; kk++) {
    int kb = kk*64 + klane;
#pragma unroll
    for (int kt = 0; kt < 2; kt++) {
      int kg = kb + kt*32;
      gload16(A  + arow0 + kg, alds + (kt*8 + 2*w    ) * 1024);
      gload16(A  + arow1 + kg, alds + (kt*8 + 2*w + 1) * 1024);
      gload16(Bt + brow0 + kg, blds + (kt*8 + 2*w    ) * 1024);
      gload16(Bt + brow1 + kg, blds + (kt*8 + 2*w + 1) * 1024);
    }
    __syncthreads();
#pragma unroll
    for (int kt = 0; kt < 2; kt++) {
      bf16x8 af[4], bfr[4];
#pragma unroll
      for (int i = 0; i < 4; i++) af[i]  = *(const bf16x8*)(alds + ((kt*8 + wm*4 + i)*64 + lane)*16);
#pragma unroll
      for (int j = 0; j < 4; j++) bfr[j] = *(const bf16x8*)(blds + ((kt*8 + wn*4 + j)*64 + lane)*16);
#pragma unroll
      for (int i = 0; i < 4; i++)
#pragma unroll
        for (int j = 0; j < 4; j++)
          acc[i][j] = mfma16(af[i], bfr[j], acc[i][j]);
    }
    __syncthreads();
  }
  int cl = lane & 15, rbase = (lane >> 4) * 4;
#pragma unroll
  for (int i = 0; i < 4; i++) {
    int gm = mblk*128 + wm*64 + i*16 + rbase;
#pragma unroll
    for (int j = 0; j < 4; j++) {
      int gn = nblk*128 + wn*64 + j*16 + cl;
      float bv = bias[gn];
#pragma unroll
      for (int r = 0; r < 4; r++)
        C[(size_t)(gm + r) * NH3 + gn] = __float2bfloat16(acc[i][j][r] + bv);
    }
  }
}

// =====================================================================================
// gru_scan, round 3: tagged exchange REBUILT FROM PROVEN PRIMITIVES.
// Round-2 post-mortem: container died (timeout) with no mismatch -> the spin never saw
// the tags. Prime suspect: hand-rolled `sc0 sc1` cache bits in inline-asm loads may not
// force a read past the XCD-private L2 (stale line -> infinite spin). This version uses
// ONLY __hip_atomic_load/store relaxed-agent (the exact primitives the 3489us baseline
// protocol used) for the exchange:
//   slot u64 = {data32 (2 bf16), tag32},  2 slots per lane per step.
//   publisher: 2x ast;  consumer: 8x ald per poll (independent -> ~1 LLC trip),
//   accept when all 8 tags == tagbase+t. Readiness and payload arrive together:
//   1 coherent round trip replaces the old 4 (publish-drain -> counter -> poll -> load).
// xbuf parity-double-buffered (slot reuse 2 steps apart; the per-step barrier chain
// orders every consumer read before the overwrite). LDS h_raw double-buffered -> ONE
// __syncthreads per step. Tags strictly increase across layers; xbuf zeroed per launch.
// HANG-PROOF: volatile deadflag escalates on first spin timeout (2^17 iters) -> block
// permanently stops spinning and finishes fast with garbage => bench reports a
// mismatch instead of a container timeout.
// =====================================================================================
__global__ void __launch_bounds__(512, 2) gru_scan_kernel(
    const bf16*  __restrict__ wuT,   // [NH3][NH] bf16 (this layer)
    const float* __restrict__ br,    // [NH3] recurrent bias
    const bf16*  __restrict__ xp,    // [NM][NH3] bf16, row = t*NB + b (bias folded)
    bf16*        __restrict__ seq,   // [NT+1][B][H] bf16; slot 256 on entry = prev layer h_255
    float*       __restrict__ hlast, // [B][H] fp32 carry handoff (in: prev layer, out: ours)
    float*       __restrict__ out,   // layer2: d_out; else null
    u64*         __restrict__ xbuf,  // [2 parity][128 rows][256 slots] u64 {data32,tag32}
    unsigned tagbase, int layer)     // tagbase = layer*NT
{
  __shared__ __align__(16) char h_raw[2][16384];   // dbuf B-frags: [kt(16)][lane(64)]*16B
  __shared__ volatile int deadflag;
  int tid = threadIdx.x, lane = tid & 63, w = tid >> 6;   // 8 waves
  int g = blockIdx.x >> 2, c = blockIdx.x & 3;
  int bb0 = g * 16;
  int r16 = lane & 15, h4 = lane >> 4;
  int srow = tid & 15, ssc = tid >> 4;                    // staging (row, chunk)
  if (tid == 0) deadflag = 0;

  // ---- hoist weight A-fragments (loop-invariant): 3 x 16 x bf16x8 ----
  bf16x8 wf[3][16];
  float  bv[3][4];
#pragma unroll
  for (int G = 0; G < 3; G++) {
    const bf16* wrow = wuT + ((size_t)(G*NH + c*128 + w*16 + r16)) * NH + h4*8;
#pragma unroll
    for (int kt = 0; kt < 16; kt++) wf[G][kt] = *(const bf16x8*)(wrow + kt*32);
#pragma unroll
    for (int q = 0; q < 4; q++) bv[G][q] = br[G*NH + c*128 + w*16 + h4*4 + q];
  }

  // ---- fp32 carry: this lane's 4 h-elements ----
  float hreg[4];
  if (layer == 0) {
    hreg[0] = hreg[1] = hreg[2] = hreg[3] = 0.0f;
  } else {
    const float* hsrc = hlast + (size_t)(bb0 + r16) * NH + c*128 + w*16 + h4*4;
    float4 v = *(const float4*)hsrc;          // prev kernel's output: plain load OK
    hreg[0] = v.x; hreg[1] = v.y; hreg[2] = v.z; hreg[3] = v.w;
  }

  u64* seqU = (u64*)seq;
  const size_t PARU = (size_t)128 * 256;       // u64 slots per parity
  // publisher slot pair: row bb0+r16, chunk c*32+w*4+h4 -> slots 2*chunk, 2*chunk+1
  u64* pubp = xbuf + ((size_t)(bb0 + r16) * 256 + (size_t)(c*64 + w*8 + h4*2));

  for (int t = 0; t < NT; t++) {
    // ---- stage h_prev [16x512] into B-fragment layout, buffer t&1 ----
    if (t == 0) {
      if (layer == 0) {
        *(int4*)(h_raw[0] + tid*32)      = (int4){0,0,0,0};
        *(int4*)(h_raw[0] + tid*32 + 16) = (int4){0,0,0,0};
      } else {   // prev layer's h_255 in seq slot 256 (previous dispatch)
        const u64* src = seqU + ((size_t)NT*NBH + (size_t)(bb0 + srow)*NH) / 4;
#pragma unroll
        for (int d = 0; d < 2; d++) {
          int sc = ssc + d*32;           // 16B chunk sc of row srow: k = sc*8..+8
          u64 q0 = ald(src + sc*2), q1 = ald(src + sc*2 + 1);
          u64* dst = (u64*)(h_raw[0] + (((sc >> 2)*64) + (sc & 3)*16 + srow)*16);
          dst[0] = q0; dst[1] = q1;
        }
      }
    } else {
      const u64* sb = xbuf + (size_t)(t & 1)*PARU + (size_t)(bb0 + srow)*256;
      unsigned want = tagbase + (unsigned)t;
      int j0 = ssc, j1 = ssc + 32, j2 = ssc + 64, j3 = ssc + 96;
      u64 a0=0, a1=0, b0=0, b1=0, c0=0, c1=0, d0=0, d1=0;
      int it = 0;
      while (!deadflag) {
        a0 = ald(sb + 2*j0); a1 = ald(sb + 2*j0 + 1);
        b0 = ald(sb + 2*j1); b1 = ald(sb + 2*j1 + 1);
        c0 = ald(sb + 2*j2); c1 = ald(sb + 2*j2 + 1);
        d0 = ald(sb + 2*j3); d1 = ald(sb + 2*j3 + 1);
        bool ok = ((unsigned)(a0 >> 32) == want) & ((unsigned)(a1 >> 32) == want) &
                  ((unsigned)(b0 >> 32) == want) & ((unsigned)(b1 >> 32) == want) &
                  ((unsigned)(c0 >> 32) == want) & ((unsigned)(c1 >> 32) == want) &
                  ((unsigned)(d0 >> 32) == want) & ((unsigned)(d1 >> 32) == want);
        if (ok) break;
        if (++it > (1 << 17)) { deadflag = 1; break; }   // escalate: never hang
      }
      char* hb = h_raw[t & 1];
      // chunk j holds h cols [j*4, j*4+4): 8B payload = lo32(slot0) | lo32(slot1)<<32
      *(u64*)(hb + (((j0>>3)*64 + ((j0>>1)&3)*16 + srow)*16 + (j0&1)*8)) =
          (u64)(unsigned)a0 | ((u64)(unsigned)a1 << 32);
      *(u64*)(hb + (((j1>>3)*64 + ((j1>>1)&3)*16 + srow)*16 + (j1&1)*8)) =
          (u64)(unsigned)b0 | ((u64)(unsigned)b1 << 32);
      *(u64*)(hb + (((j2>>3)*64 + ((j2>>1)&3)*16 + srow)*16 + (j2&1)*8)) =
          (u64)(unsigned)c0 | ((u64)(unsigned)c1 << 32);
      *(u64*)(hb + (((j3>>3)*64 + ((j3>>1)&3)*16 + srow)*16 + (j3&1)*8)) =
          (u64)(unsigned)d0 | ((u64)(unsigned)d1 << 32);
    }

    // xp_t prefetch (plain loads; written by an earlier dispatch) — hides under barrier/MFMA
    const u64* xq = (const u64*)(xp + ((size_t)t*NB + bb0 + r16)*NH3 + c*128 + w*16 + h4*4);
    u64 xv0 = xq[0], xv1 = xq[128], xv2 = xq[256];

    __syncthreads();                   // staging visible to all waves (only barrier/step)

    // ---- rec^T = Wu_cols x h : 3 tiles/wave, K=512, weights in registers ----
    const char* hbR = h_raw[t & 1];
    floatx4 ac0 = (floatx4){0,0,0,0}, ac1 = (floatx4){0,0,0,0}, ac2 = (floatx4){0,0,0,0};
#pragma unroll
    for (int kt = 0; kt < 16; kt++) {
      bf16x8 hb = *(const bf16x8*)(hbR + (kt*64 + lane)*16);
      ac0 = mfma16(wf[0][kt], hb, ac0);
      ac1 = mfma16(wf[1][kt], hb, ac1);
      ac2 = mfma16(wf[2][kt], hb, ac2);
    }

    // ---- gates in registers ----
    unsigned short pk[4];
#pragma unroll
    for (int q = 0; q < 4; q++) {
      float rz = ac0[q] + bv[0][q];
      float rr = ac1[q] + bv[1][q];
      float rh = ac2[q] + bv[2][q];
      float xz = b2f((unsigned short)(xv0 >> (16*q)));
      float xr = b2f((unsigned short)(xv1 >> (16*q)));
      float xh = b2f((unsigned short)(xv2 >> (16*q)));
      float z  = fsig(xz + rz);
      float r  = fsig(xr + rr);
      float hh = ftanh(xh + r * rh);
      float hn = z * hreg[q] + (1.0f - z) * hh;
      hreg[q] = hn;
      pk[q] = f2b(hn);
    }
    u64 pv; __builtin_memcpy(&pv, pk, 8);

    // ---- tagged publish FIRST (critical path): 2x 8B relaxed-agent atomic stores ----
    if (t < NT - 1) {
      u64 tg = (u64)(tagbase + (unsigned)t + 1u) << 32;
      u64* pp = pubp + (size_t)((t + 1) & 1) * PARU;
      ast(pp,     ((u64)(unsigned)(pv & 0xffffffffu)) | tg);
      ast(pp + 1, ((u64)(unsigned)(pv >> 32))         | tg);
    }
    // seq slot t+1 for the next layer's GEMM (plain store; dispatch-boundary coherence)
    if (layer != 2)
      seqU[((size_t)(t+1)*NBH + (size_t)(bb0 + r16)*NH)/4 + c*32 + w*4 + h4] = pv;

    if (layer == 2) {                  // fp32 chain straight into d_out [B][T][H] flat
      float* o = out + ((size_t)(bb0 + r16)*NT + t)*NH + c*128 + w*16 + h4*4;
      *(float4*)o = (float4){hreg[0], hreg[1], hreg[2], hreg[3]};
      if (t == NT - 1) {               // final state tail [B][H]
        float* o2 = out + (size_t)NM*NH + (size_t)(bb0 + r16)*NH + c*128 + w*16 + h4*4;
        *(float4*)o2 = (float4){hreg[0], hreg[1], hreg[2], hreg[3]};
      }
    } else if (t == NT - 1) {          // fp32 carry handoff for next layer (plain store)
      float* o = hlast + (size_t)(bb0 + r16)*NH + c*128 + w*16 + h4*4;
      *(float4*)o = (float4){hreg[0], hreg[1], hreg[2], hreg[3]};
    }
    // no trailing barrier: LDS dbuf + (staging(t+2) transitively follows barrier(t+1))
  }
}

extern "C" void kernel_launch(void* const* d_in, const int* in_sizes, int n_in,
                              void* d_out, int out_size, void* d_ws, size_t ws_size,
                              hipStream_t stream) {
  const float* x   = (const float*)d_in[0];
  const float* wk  = (const float*)d_in[1];
  const float* wu  = (const float*)d_in[2];
  const float* bis = (const float*)d_in[3];
  float* out = (float*)d_out;

  // workspace layout:
  //   wkT   @ 0            4,718,592   [3][1536][512] bf16
  //   wuT   @ 4,718,592    4,718,592
  //   xp    @ 9,437,184  100,663,296   [32768][1536] bf16
  //   seq   @ 110,100,480 33,685,504   [257][128][512] bf16 (xb aliases base)
  //   hlast @ 143,785,984    262,144   [128][512] fp32
  //   xbuf  @ 144,048,128    524,288   [2][128][256] u64 tagged slots
  const size_t REQ = 144572416;
  if (ws_size < REQ) {
    hipMemsetAsync(d_out, 0, (size_t)out_size * 4, stream);
    return;
  }
  char* ws = (char*)d_ws;
  bf16*  wkT   = (bf16*)(ws);
  bf16*  wuT   = (bf16*)(ws + 4718592);
  bf16*  xp    = (bf16*)(ws + 9437184);
  bf16*  seq   = (bf16*)(ws + 110100480);
  bf16*  xb    = seq;                          // alias: dead after layer-0 GEMM
  float* hlast = (float*)(ws + 143785984);
  u64*   xbuf  = (u64*)(ws + 144048128);

  hipMemsetAsync(xbuf, 0, 524288, stream);     // zero tags: no cross-replay aliasing
  transpose_cvt_kernel<<<dim3(48,16,3), dim3(32,8), 0, stream>>>(wk, wkT);
  transpose_cvt_kernel<<<dim3(48,16,3), dim3(32,8), 0, stream>>>(wu, wuT);
  cvt_x_kernel<<<(NM*NH/4)/256, 256, 0, stream>>>(x, xb);

  const size_t WS = (size_t)NH3 * NH;   // per-layer weight stride

  // layer 0
  gemm_xp_kernel<<<dim3(256,12), 256, 0, stream>>>(xb, wkT, bis + 0*2*NH3, xp, 0);
  gru_scan_kernel<<<32, 512, 0, stream>>>(wuT, bis + 0*2*NH3 + NH3, xp,
      seq, hlast, nullptr, xbuf, 0u, 0);
  // layer 1 (gemm reads seq slots 1..256 = layer-0 h)
  gemm_xp_kernel<<<dim3(256,12), 256, 0, stream>>>(seq + NBH, wkT + WS, bis + 1*2*NH3, xp, 1);
  gru_scan_kernel<<<32, 512, 0, stream>>>(wuT + WS, bis + 1*2*NH3 + NH3, xp,
      seq, hlast, nullptr, xbuf, 256u, 1);
  // layer 2 (fp32 chain straight into d_out)
  gemm_xp_kernel<<<dim3(256,12), 256, 0, stream>>>(seq + NBH, wkT + 2*WS, bis + 2*2*NH3, xp, 1);
  gru_scan_kernel<<<32, 512, 0, stream>>>(wuT + 2*WS, bis + 2*2*NH3 + NH3, xp,
      seq, hlast, out, xbuf, 512u, 2);

  (void)in_sizes; (void)n_in; (void)out_size; (void)ws_size;
}

// Round 4
// 3867.781 us; speedup vs baseline: 1.2311x; 1.2311x over previous
//
#include <hip/hip_runtime.h>
#include <hip/hip_bf16.h>

#define NL  3
#define NB  128
#define NT  256
#define NH  512
#define NH3 1536
#define NBH (NB*NH)      // 65536
#define NM  (NB*NT)      // 32768

typedef __bf16 bf16x8 __attribute__((ext_vector_type(8)));
typedef float  floatx4 __attribute__((ext_vector_type(4)));
typedef int    intx4  __attribute__((ext_vector_type(4)));
typedef __hip_bfloat16 bf16;
typedef unsigned long long u64;

__device__ __forceinline__ floatx4 mfma16(bf16x8 a, bf16x8 b, floatx4 c) {
  return __builtin_amdgcn_mfma_f32_16x16x32_bf16(a, b, c, 0, 0, 0);
}
__device__ __forceinline__ void gload16(const void* g, void* l) {
  __builtin_amdgcn_global_load_lds(
      (const __attribute__((address_space(1))) unsigned int*)g,
      (__attribute__((address_space(3))) unsigned int*)l, 16, 0, 0);
}
__device__ __forceinline__ float fsig(float x)  { return 1.0f / (1.0f + __expf(-x)); }
__device__ __forceinline__ float ftanh(float x) { return 2.0f / (1.0f + __expf(-2.0f*x)) - 1.0f; }
__device__ __forceinline__ float b2f(unsigned short u) {
  unsigned v = (unsigned)u << 16; float f; __builtin_memcpy(&f, &v, 4); return f;
}
__device__ __forceinline__ unsigned short f2b(float f) {
  bf16 h = __float2bfloat16(f); unsigned short u; __builtin_memcpy(&u, &h, 2); return u;
}
__device__ __forceinline__ u64 ald(const u64* p) {
  return __hip_atomic_load(p, __ATOMIC_RELAXED, __HIP_MEMORY_SCOPE_AGENT);
}
__device__ __forceinline__ void ast(u64* p, u64 v) {
  __hip_atomic_store(p, v, __ATOMIC_RELAXED, __HIP_MEMORY_SCOPE_AGENT);
}

// ONE batched poll: 4x 16B device-scope loads of a contiguous 64B line, single waitcnt.
// sc1 = device scope on gfx940+ (SC1:SC0 = 1:0). Per-u64 halves are written atomically
// by 8B stores, and each u64 self-validates via its tag -> 16B loads need no atomicity.
__device__ __forceinline__ void ld64(const void* p, intx4& a, intx4& b, intx4& c, intx4& d) {
  asm volatile(
      "global_load_dwordx4 %0, %4, off sc1\n\t"
      "global_load_dwordx4 %1, %4, off offset:16 sc1\n\t"
      "global_load_dwordx4 %2, %4, off offset:32 sc1\n\t"
      "global_load_dwordx4 %3, %4, off offset:48 sc1\n\t"
      "s_waitcnt vmcnt(0)"
      : "=&v"(a), "=&v"(b), "=&v"(c), "=&v"(d)
      : "v"(p)
      : "memory");
}

// ---------- transpose + cvt weights: fp32 [NL][NH][NH3] -> bf16 [NL][NH3][NH] ----------
__global__ void transpose_cvt_kernel(const float* __restrict__ in, bf16* __restrict__ out) {
  __shared__ float tile[32][33];
  int l = blockIdx.z;
  int n0 = blockIdx.x * 32, k0 = blockIdx.y * 32;
  const float* src = in + (size_t)l * NH * NH3;
  bf16* dst = out + (size_t)l * NH3 * NH;
  int tx = threadIdx.x, ty = threadIdx.y;    // 32 x 8
#pragma unroll
  for (int i = 0; i < 4; i++)
    tile[ty + 8*i][tx] = src[(size_t)(k0 + ty + 8*i) * NH3 + n0 + tx];
  __syncthreads();
#pragma unroll
  for (int i = 0; i < 4; i++)
    dst[(size_t)(n0 + ty + 8*i) * NH + k0 + tx] = __float2bfloat16(tile[tx][ty + 8*i]);
}

// ---------- elementwise fp32 -> bf16 (x input) ----------
__global__ void cvt_x_kernel(const float* __restrict__ in, bf16* __restrict__ out) {
  size_t i = (size_t)blockIdx.x * blockDim.x + threadIdx.x;
  float4 v = ((const float4*)in)[i];
  ushort4 pk;
  pk.x = f2b(v.x); pk.y = f2b(v.y); pk.z = f2b(v.z); pk.w = f2b(v.w);
  ((ushort4*)out)[i] = pk;
}

// ---------- xp GEMM (proven): C[m][n] = A[m]@Bt[n]^T + bias[n], bf16 out ----------
__global__ void __launch_bounds__(256, 2) gemm_xp_kernel(
    const bf16* __restrict__ A, const bf16* __restrict__ Bt,
    const float* __restrict__ bias, bf16* __restrict__ C, int a_mode)
{
  __shared__ char alds[16384];
  __shared__ char blds[16384];
  int tid = threadIdx.x;
  int lane = tid & 63, w = tid >> 6;
  int mblk = blockIdx.x, nblk = blockIdx.y;
  int wm = w >> 1, wn = w & 1;
  int klane = (lane >> 4) * 8;
  int r0 = 2*w*16 + (lane & 15);
  size_t arow0, arow1;
  if (a_mode == 0) {
    arow0 = ((size_t)r0 * NT + mblk) * NH;
    arow1 = ((size_t)(r0 + 16) * NT + mblk) * NH;
  } else {
    arow0 = (size_t)(mblk*128 + r0) * NH;
    arow1 = arow0 + (size_t)16 * NH;
  }
  size_t brow0 = (size_t)(nblk*128 + 2*w*16 + (lane & 15)) * NH;
  size_t brow1 = brow0 + (size_t)16 * NH;

  floatx4 acc[4][4];
#pragma unroll
  for (int i = 0; i < 4; i++)
#pragma unroll
    for (int j = 0; j < 4; j++) acc[i][j] = (floatx4){0.f, 0.f, 0.f, 0.f};

  for (int kk = 0; kk < 8; kk++) {
    int kb = kk*64 + klane;
#pragma unroll
    for (int kt = 0; kt < 2; kt++) {
      int kg = kb + kt*32;
      gload16(A  + arow0 + kg, alds + (kt*8 + 2*w    ) * 1024);
      gload16(A  + arow1 + kg, alds + (kt*8 + 2*w + 1) * 1024);
      gload16(Bt + brow0 + kg, blds + (kt*8 + 2*w    ) * 1024);
      gload16(Bt + brow1 + kg, blds + (kt*8 + 2*w + 1) * 1024);
    }
    __syncthreads();
#pragma unroll
    for (int kt = 0; kt < 2; kt++) {
      bf16x8 af[4], bfr[4];
#pragma unroll
      for (int i = 0; i < 4; i++) af[i]  = *(const bf16x8*)(alds + ((kt*8 + wm*4 + i)*64 + lane)*16);
#pragma unroll
      for (int j = 0; j < 4; j++) bfr[j] = *(const bf16x8*)(blds + ((kt*8 + wn*4 + j)*64 + lane)*16);
#pragma unroll
      for (int i = 0; i < 4; i++)
#pragma unroll
        for (int j = 0; j < 4; j++)
          acc[i][j] = mfma16(af[i], bfr[j], acc[i][j]);
    }
    __syncthreads();
  }
  int cl = lane & 15, rbase = (lane >> 4) * 4;
#pragma unroll
  for (int i = 0; i < 4; i++) {
    int gm = mblk*128 + wm*64 + i*16 + rbase;
#pragma unroll
    for (int j = 0; j < 4; j++) {
      int gn = nblk*128 + wn*64 + j*16 + cl;
      float bv = bias[gn];
#pragma unroll
      for (int r = 0; r < 4; r++)
        C[(size_t)(gm + r) * NH3 + gn] = __float2bfloat16(acc[i][j][r] + bv);
    }
  }
}

// =====================================================================================
// gru_scan, round 4: tagged exchange with CONSUMER-MAJOR slots + BATCHED 1-RT poll.
// Round-3 post-mortem: protocol correct but 5.64us/step ~= 8 serialized LLC/HBM round
// trips -> the 8 per-slot __hip_atomic_loads were NOT batched (per-atomic waitcnt) and
// each thread's slots spanned 4 cache lines 512B apart. Fix:
//  (1) xbuf permuted so each consumer thread's 8 tagged u64 slots are ONE contiguous
//      64B-aligned line at xbuf[parity] + g*4096 + tid*8  (ssc*16+srow == tid).
//      Producer (block c, thread w,lane) writes 2 contiguous slots at
//      (w*4+h4)*16*8 + r16*8 + c*2  -- 16B per producer, off critical path.
//  (2) fast poll: ONE inline-asm block, 4x global_load_dwordx4 sc1 (device scope),
//      single s_waitcnt -> 1 round trip per poll. Tags validate per-u64 (8B halves
//      are atomically stored; 16B loads need no 16B atomicity).
//  (3) safety: if 8 fast polls miss, permanently fall back to the round-3-PROVEN
//      per-slot ald loop (+ deadflag escape) -> worst case = round-3 perf, never a
//      hang, and the outcome diagnoses sc1-load visibility of ast stores.
// Everything else byte-identical to round 3 (which PASSED): parity-dbuf xbuf (ABA-safe
// via the per-step barrier chain), dbuf LDS h_raw -> ONE __syncthreads per step,
// strictly-increasing tags, xbuf zeroed per launch, t==0 seq-slot-256 handoff.
// =====================================================================================
__global__ void __launch_bounds__(512, 2) gru_scan_kernel(
    const bf16*  __restrict__ wuT,   // [NH3][NH] bf16 (this layer)
    const float* __restrict__ br,    // [NH3] recurrent bias
    const bf16*  __restrict__ xp,    // [NM][NH3] bf16, row = t*NB + b (bias folded)
    bf16*        __restrict__ seq,   // [NT+1][B][H] bf16; slot 256 on entry = prev layer h_255
    float*       __restrict__ hlast, // [B][H] fp32 carry handoff (in: prev layer, out: ours)
    float*       __restrict__ out,   // layer2: d_out; else null
    u64*         __restrict__ xbuf,  // [2 parity][8 grp][512 tid][8] u64 {data32,tag32}
    unsigned tagbase, int layer)     // tagbase = layer*NT
{
  __shared__ __align__(16) char h_raw[2][16384];   // dbuf B-frags: [kt(16)][lane(64)]*16B
  __shared__ volatile int deadflag;
  int tid = threadIdx.x, lane = tid & 63, w = tid >> 6;   // 8 waves
  int g = blockIdx.x >> 2, c = blockIdx.x & 3;
  int bb0 = g * 16;
  int r16 = lane & 15, h4 = lane >> 4;
  int srow = tid & 15, ssc = tid >> 4;                    // staging (row, chunk-col)
  if (tid == 0) deadflag = 0;

  // ---- hoist weight A-fragments (loop-invariant): 3 x 16 x bf16x8 ----
  bf16x8 wf[3][16];
  float  bv[3][4];
#pragma unroll
  for (int G = 0; G < 3; G++) {
    const bf16* wrow = wuT + ((size_t)(G*NH + c*128 + w*16 + r16)) * NH + h4*8;
#pragma unroll
    for (int kt = 0; kt < 16; kt++) wf[G][kt] = *(const bf16x8*)(wrow + kt*32);
#pragma unroll
    for (int q = 0; q < 4; q++) bv[G][q] = br[G*NH + c*128 + w*16 + h4*4 + q];
  }

  // ---- fp32 carry: this lane's 4 h-elements ----
  float hreg[4];
  if (layer == 0) {
    hreg[0] = hreg[1] = hreg[2] = hreg[3] = 0.0f;
  } else {
    const float* hsrc = hlast + (size_t)(bb0 + r16) * NH + c*128 + w*16 + h4*4;
    float4 v = *(const float4*)hsrc;          // prev kernel's output: plain load OK
    hreg[0] = v.x; hreg[1] = v.y; hreg[2] = v.z; hreg[3] = v.w;
  }

  u64* seqU = (u64*)seq;
  const size_t PARU = (size_t)8 * 512 * 8;     // 32768 u64 slots per parity (256KB)
  // producer slot pair (consumer-major layout): consumer tid' = (w*4+h4)*16 + r16,
  // chunk index within consumer = c  ->  slots tid'*8 + c*2 + {0,1}
  u64* pubp = xbuf + (size_t)g*4096 + ((size_t)((w*4 + h4)*16 + r16))*8 + (size_t)(c*2);
  bool fastok = true;

  for (int t = 0; t < NT; t++) {
    // ---- stage h_prev [16x512] into B-fragment layout, buffer t&1 ----
    if (t == 0) {
      if (layer == 0) {
        *(int4*)(h_raw[0] + tid*32)      = (int4){0,0,0,0};
        *(int4*)(h_raw[0] + tid*32 + 16) = (int4){0,0,0,0};
      } else {   // prev layer's h_255 in seq slot 256 (previous dispatch)
        const u64* src = seqU + ((size_t)NT*NBH + (size_t)(bb0 + srow)*NH) / 4;
#pragma unroll
        for (int d = 0; d < 2; d++) {
          int sc = ssc + d*32;           // 16B chunk sc of row srow: k = sc*8..+8
          u64 q0 = ald(src + sc*2), q1 = ald(src + sc*2 + 1);
          u64* dst = (u64*)(h_raw[0] + (((sc >> 2)*64) + (sc & 3)*16 + srow)*16);
          dst[0] = q0; dst[1] = q1;
        }
      }
    } else {
      const u64* sb = xbuf + (size_t)(t & 1)*PARU + (size_t)g*4096 + (size_t)tid*8;
      unsigned want = tagbase + (unsigned)t;
      int w_ = (int)want;
      u64 q0 = 0, q1 = 0, q2 = 0, q3 = 0;
      bool got = false;
      if (fastok) {                       // 1-RT batched poll (64B contiguous line)
        for (int it = 0; it < 8; ++it) {
          intx4 A, B2, C2, D2;
          ld64(sb, A, B2, C2, D2);
          if (A.y == w_ && A.w == w_ && B2.y == w_ && B2.w == w_ &&
              C2.y == w_ && C2.w == w_ && D2.y == w_ && D2.w == w_) {
            q0 = (u64)(unsigned)A.x  | ((u64)(unsigned)A.z  << 32);
            q1 = (u64)(unsigned)B2.x | ((u64)(unsigned)B2.z << 32);
            q2 = (u64)(unsigned)C2.x | ((u64)(unsigned)C2.z << 32);
            q3 = (u64)(unsigned)D2.x | ((u64)(unsigned)D2.z << 32);
            got = true; break;
          }
        }
        if (!got) fastok = false;         // sc1 blind or slow producer: go proven path
      }
      if (!got) {                         // round-3-proven per-slot atomic loads
        int it = 0;
        while (!deadflag) {
          u64 a0 = ald(sb+0), a1 = ald(sb+1), b0 = ald(sb+2), b1 = ald(sb+3);
          u64 c0 = ald(sb+4), c1 = ald(sb+5), d0 = ald(sb+6), d1 = ald(sb+7);
          bool ok = ((unsigned)(a0 >> 32) == want) & ((unsigned)(a1 >> 32) == want) &
                    ((unsigned)(b0 >> 32) == want) & ((unsigned)(b1 >> 32) == want) &
                    ((unsigned)(c0 >> 32) == want) & ((unsigned)(c1 >> 32) == want) &
                    ((unsigned)(d0 >> 32) == want) & ((unsigned)(d1 >> 32) == want);
          if (ok) {
            q0 = (u64)(unsigned)a0 | ((u64)(unsigned)a1 << 32);
            q1 = (u64)(unsigned)b0 | ((u64)(unsigned)b1 << 32);
            q2 = (u64)(unsigned)c0 | ((u64)(unsigned)c1 << 32);
            q3 = (u64)(unsigned)d0 | ((u64)(unsigned)d1 << 32);
            break;
          }
          if (++it > (1 << 17)) { deadflag = 1; break; }   // escalate: never hang
        }
      }
      // chunk j = ssc + 32k holds h cols [j*4, j*4+4) of row srow
      char* hb = h_raw[t & 1];
      int j0 = ssc, j1 = ssc + 32, j2 = ssc + 64, j3 = ssc + 96;
      *(u64*)(hb + (((j0>>3)*64 + ((j0>>1)&3)*16 + srow)*16 + (j0&1)*8)) = q0;
      *(u64*)(hb + (((j1>>3)*64 + ((j1>>1)&3)*16 + srow)*16 + (j1&1)*8)) = q1;
      *(u64*)(hb + (((j2>>3)*64 + ((j2>>1)&3)*16 + srow)*16 + (j2&1)*8)) = q2;
      *(u64*)(hb + (((j3>>3)*64 + ((j3>>1)&3)*16 + srow)*16 + (j3&1)*8)) = q3;
    }

    // xp_t prefetch (plain loads; written by an earlier dispatch) — hides under barrier/MFMA
    const u64* xq = (const u64*)(xp + ((size_t)t*NB + bb0 + r16)*NH3 + c*128 + w*16 + h4*4);
    u64 xv0 = xq[0], xv1 = xq[128], xv2 = xq[256];

    __syncthreads();                   // staging visible to all waves (only barrier/step)

    // ---- rec^T = Wu_cols x h : 3 tiles/wave, K=512, weights in registers ----
    const char* hbR = h_raw[t & 1];
    floatx4 ac0 = (floatx4){0,0,0,0}, ac1 = (floatx4){0,0,0,0}, ac2 = (floatx4){0,0,0,0};
#pragma unroll
    for (int kt = 0; kt < 16; kt++) {
      bf16x8 hb = *(const bf16x8*)(hbR + (kt*64 + lane)*16);
      ac0 = mfma16(wf[0][kt], hb, ac0);
      ac1 = mfma16(wf[1][kt], hb, ac1);
      ac2 = mfma16(wf[2][kt], hb, ac2);
    }

    // ---- gates in registers ----
    unsigned short pk[4];
#pragma unroll
    for (int q = 0; q < 4; q++) {
      float rz = ac0[q] + bv[0][q];
      float rr = ac1[q] + bv[1][q];
      float rh = ac2[q] + bv[2][q];
      float xz = b2f((unsigned short)(xv0 >> (16*q)));
      float xr = b2f((unsigned short)(xv1 >> (16*q)));
      float xh = b2f((unsigned short)(xv2 >> (16*q)));
      float z  = fsig(xz + rz);
      float r  = fsig(xr + rr);
      float hh = ftanh(xh + r * rh);
      float hn = z * hreg[q] + (1.0f - z) * hh;
      hreg[q] = hn;
      pk[q] = f2b(hn);
    }
    u64 pv; __builtin_memcpy(&pv, pk, 8);

    // ---- tagged publish FIRST (critical path): 2x 8B relaxed-agent atomic stores ----
    if (t < NT - 1) {
      u64 tg = (u64)(tagbase + (unsigned)t + 1u) << 32;
      u64* pp = pubp + (size_t)((t + 1) & 1) * PARU;
      ast(pp,     ((u64)(unsigned)(pv & 0xffffffffu)) | tg);
      ast(pp + 1, ((u64)(unsigned)(pv >> 32))         | tg);
    }
    // seq slot t+1 for the next layer's GEMM (plain store; dispatch-boundary coherence)
    if (layer != 2)
      seqU[((size_t)(t+1)*NBH + (size_t)(bb0 + r16)*NH)/4 + c*32 + w*4 + h4] = pv;

    if (layer == 2) {                  // fp32 chain straight into d_out [B][T][H] flat
      float* o = out + ((size_t)(bb0 + r16)*NT + t)*NH + c*128 + w*16 + h4*4;
      *(float4*)o = (float4){hreg[0], hreg[1], hreg[2], hreg[3]};
      if (t == NT - 1) {               // final state tail [B][H]
        float* o2 = out + (size_t)NM*NH + (size_t)(bb0 + r16)*NH + c*128 + w*16 + h4*4;
        *(float4*)o2 = (float4){hreg[0], hreg[1], hreg[2], hreg[3]};
      }
    } else if (t == NT - 1) {          // fp32 carry handoff for next layer (plain store)
      float* o = hlast + (size_t)(bb0 + r16)*NH + c*128 + w*16 + h4*4;
      *(float4*)o = (float4){hreg[0], hreg[1], hreg[2], hreg[3]};
    }
    // no trailing barrier: LDS dbuf + (staging(t+2) transitively follows barrier(t+1))
  }
}

extern "C" void kernel_launch(void* const* d_in, const int* in_sizes, int n_in,
                              void* d_out, int out_size, void* d_ws, size_t ws_size,
                              hipStream_t stream) {
  const float* x   = (const float*)d_in[0];
  const float* wk  = (const float*)d_in[1];
  const float* wu  = (const float*)d_in[2];
  const float* bis = (const float*)d_in[3];
  float* out = (float*)d_out;

  // workspace layout:
  //   wkT   @ 0            4,718,592   [3][1536][512] bf16
  //   wuT   @ 4,718,592    4,718,592
  //   xp    @ 9,437,184  100,663,296   [32768][1536] bf16
  //   seq   @ 110,100,480 33,685,504   [257][128][512] bf16 (xb aliases base)
  //   hlast @ 143,785,984    262,144   [128][512] fp32
  //   xbuf  @ 144,048,128    524,288   [2][8][512][8] u64 tagged slots (consumer-major)
  const size_t REQ = 144572416;
  if (ws_size < REQ) {
    hipMemsetAsync(d_out, 0, (size_t)out_size * 4, stream);
    return;
  }
  char* ws = (char*)d_ws;
  bf16*  wkT   = (bf16*)(ws);
  bf16*  wuT   = (bf16*)(ws + 4718592);
  bf16*  xp    = (bf16*)(ws + 9437184);
  bf16*  seq   = (bf16*)(ws + 110100480);
  bf16*  xb    = seq;                          // alias: dead after layer-0 GEMM
  float* hlast = (float*)(ws + 143785984);
  u64*   xbuf  = (u64*)(ws + 144048128);

  hipMemsetAsync(xbuf, 0, 524288, stream);     // zero tags: no cross-replay aliasing
  transpose_cvt_kernel<<<dim3(48,16,3), dim3(32,8), 0, stream>>>(wk, wkT);
  transpose_cvt_kernel<<<dim3(48,16,3), dim3(32,8), 0, stream>>>(wu, wuT);
  cvt_x_kernel<<<(NM*NH/4)/256, 256, 0, stream>>>(x, xb);

  const size_t WS = (size_t)NH3 * NH;   // per-layer weight stride

  // layer 0
  gemm_xp_kernel<<<dim3(256,12), 256, 0, stream>>>(xb, wkT, bis + 0*2*NH3, xp, 0);
  gru_scan_kernel<<<32, 512, 0, stream>>>(wuT, bis + 0*2*NH3 + NH3, xp,
      seq, hlast, nullptr, xbuf, 0u, 0);
  // layer 1 (gemm reads seq slots 1..256 = layer-0 h)
  gemm_xp_kernel<<<dim3(256,12), 256, 0, stream>>>(seq + NBH, wkT + WS, bis + 1*2*NH3, xp, 1);
  gru_scan_kernel<<<32, 512, 0, stream>>>(wuT + WS, bis + 1*2*NH3 + NH3, xp,
      seq, hlast, nullptr, xbuf, 256u, 1);
  // layer 2 (fp32 chain straight into d_out)
  gemm_xp_kernel<<<dim3(256,12), 256, 0, stream>>>(seq + NBH, wkT + 2*WS, bis + 2*2*NH3, xp, 1);
  gru_scan_kernel<<<32, 512, 0, stream>>>(wuT + 2*WS, bis + 2*2*NH3 + NH3, xp,
      seq, hlast, out, xbuf, 512u, 2);

  (void)in_sizes; (void)n_in; (void)out_size; (void)ws_size;
}